// Round 7
// baseline (1106.278 us; speedup 1.0000x reference)
//
#include <hip/hip_runtime.h>

// RetinaNet 3D head via bf16 MFMA implicit GEMM, latency-optimized.
// 2 heads x 4 levels (S=32,16,8,4; vox 32768,4096,512,64; total 37440).
// Activations: zero-padded channel-last bf16 [pvox][64], cin stored in a
// PERMUTED order c2s(c) so one 32B per-lane load covers both K=32 MFMA
// blocks. Weights bf16 [tap][cout][perm cin]. Conv: 27 taps x 2 K-blocks of
// mfma_f32_16x16x32_bf16, reg-double-buffered loads, no LDS/barriers.
// Conv writes RAW bf16 (pre-norm) to an unpadded buffer + fused IN stats;
// norm pass reads raw, applies InstanceNorm+PReLU, writes padded dst
// (strict producer->consumer; no cross-kernel in-place RMW — round-6 replay
// divergence was traced to that pattern).

typedef __attribute__((ext_vector_type(8)))  short short8;
typedef __attribute__((ext_vector_type(16))) short short16;
typedef __attribute__((ext_vector_type(8)))  unsigned short ushort8;
typedef __attribute__((ext_vector_type(4)))  float f32x4;

static constexpr int TOTVOX    = 37440;
static constexpr int CLS_TOTAL = 673920;                  // 18 * 37440
static constexpr int TOTPADV   = 46352;                   // 39304+5832+1000+216
static constexpr size_t PAD_HSTRIDE_E = (size_t)TOTPADV * 64;  // elems per head
static constexpr size_t RAW_HSTRIDE_E = (size_t)TOTVOX * 64;
static constexpr size_t WLAYER_E = 2u * 27 * 4096;        // elems per layer (2 heads)

__device__ __forceinline__ unsigned short f2b(float x) {
    unsigned int u = __float_as_uint(x);
    u += 0x7FFFu + ((u >> 16) & 1u);
    return (unsigned short)(u >> 16);
}
__device__ __forceinline__ float b2f(unsigned short h) {
    return __uint_as_float(((unsigned)h) << 16);
}
// storage slot -> original channel ; original channel -> storage slot
__device__ __forceinline__ int s2c(int s) { return ((s >> 3) & 1) * 32 + (s >> 4) * 8 + (s & 7); }
__device__ __forceinline__ int c2s(int c) { return ((c >> 3) & 3) * 16 + (c >> 5) * 8 + (c & 7); }

// bijective XCD swizzle for nwg=1170 (q=146, r=2), m204 form
__device__ __forceinline__ int xcdswz(int orig) {
    const int xcd = orig & 7;
    return (xcd < 2 ? xcd * 147 : 294 + (xcd - 2) * 146) + (orig >> 3);
}

// 32-voxel block decomposition: b in [0,1170): l0:1024, l1:128, l2:16, l3:2
__device__ __forceinline__ void blkdec(int b, int& lvl, int& ls, int& S, int& P,
                                       int& loff, int& cvol, int& base)
{
    if (b < 1024)      { lvl = 0; base = b * 32; }
    else if (b < 1152) { lvl = 1; base = 32768 + (b - 1024) * 32; }
    else if (b < 1168) { lvl = 2; base = 36864 + (b - 1152) * 32; }
    else               { lvl = 3; base = 37376 + (b - 1168) * 32; }
    ls = 5 - lvl; S = 1 << ls; P = S + 2;
    loff = (lvl == 0) ? 0 : (lvl == 1) ? 32768 : (lvl == 2) ? 36864 : 37376;
    cvol = (lvl == 0) ? 0 : (lvl == 1) ? 39304 : (lvl == 2) ? 45136 : 46136;
}

__device__ __forceinline__ void voxdec(int vox, int& lvl, int& ls, int& loff,
                                       int& cvol, int& pbase)
{
    if (vox < 32768)      lvl = 0;
    else if (vox < 36864) lvl = 1;
    else if (vox < 37376) lvl = 2;
    else                  lvl = 3;
    ls = 5 - lvl;
    const int S = 1 << ls, P = S + 2;
    loff = (lvl == 0) ? 0 : (lvl == 1) ? 32768 : (lvl == 2) ? 36864 : 37376;
    cvol = (lvl == 0) ? 0 : (lvl == 1) ? 39304 : (lvl == 2) ? 45136 : 46136;
    const int v = vox - loff;
    const int x = v & (S - 1), y = (v >> ls) & (S - 1), z = v >> (2 * ls);
    pbase = ((z + 1) * P + (y + 1)) * P + (x + 1);
}

// ---------------------------------------------------------------------------
// Weight conversion -> bf16 [layer][head][tap][cout(64)][perm cin(64)].
// ---------------------------------------------------------------------------
__global__ __launch_bounds__(256) void wconv_kernel(
    const float* __restrict__ cls_w1, const float* __restrict__ reg_w1,
    const float* __restrict__ cls_w234, const float* __restrict__ reg_w234,
    const float* __restrict__ cls_wf, const float* __restrict__ reg_wf,
    unsigned short* __restrict__ dst)
{
    const int id = blockIdx.x * 256 + (int)threadIdx.x;   // < 1,105,920
    const int s  = id / 221184;
    const int r  = id - s * 221184;
    const int head = r / 110592;
    const int r2 = r - head * 110592;
    const int t  = r2 >> 12;
    const int co = (r2 >> 6) & 63;
    const int cio = s2c(r2 & 63);

    float val = 0.0f;
    if (s == 0) {
        if (cio < 36) {
            const float* w = head ? reg_w1 : cls_w1;      // [64][36][27]
            val = w[(co * 36 + cio) * 27 + t];
        }
    } else if (s <= 3) {
        const float* w = (head ? reg_w234 : cls_w234) + (size_t)(s - 1) * 110592;
        val = w[(co * 64 + cio) * 27 + t];                // [64][64][27]
    } else {
        const int OUT = head ? 54 : 18;
        if (co < OUT) {
            const float* w = head ? reg_wf : cls_wf;      // [OUT][64][27]
            val = w[(co * 64 + cio) * 27 + t];
        }
    }
    dst[id] = f2b(val);
}

// ---------------------------------------------------------------------------
// Input conversion: p0..p3 fp32 [36][nvox] -> padded bf16 [pvox][64] permuted.
// ---------------------------------------------------------------------------
__global__ __launch_bounds__(256) void inconv_kernel(
    const float* __restrict__ p0, const float* __restrict__ p1,
    const float* __restrict__ p2, const float* __restrict__ p3,
    unsigned short* __restrict__ padin)
{
    const int id = blockIdx.x * 256 + (int)threadIdx.x;   // < 299,520
    const int cbi = id / 37440;
    const int vox = id - cbi * 37440;
    const int s0 = cbi * 8;

    int lvl, ls, loff, cvol, pbase;
    voxdec(vox, lvl, ls, loff, cvol, pbase);
    const int nvox = 1 << (3 * ls);
    const int lvox = vox - loff;
    const float* src = (lvl == 0) ? p0 : (lvl == 1) ? p1 : (lvl == 2) ? p2 : p3;

    ushort8 o;
    #pragma unroll
    for (int j = 0; j < 8; ++j) {
        const int c = s2c(s0 + j);
        o[j] = (c < 36) ? f2b(src[c * nvox + lvox]) : (unsigned short)0;
    }
    *reinterpret_cast<ushort8*>(padin + ((size_t)(cvol + pbase) * 64 + s0)) = o;
}

// ---------------------------------------------------------------------------
// Conv layer: implicit GEMM. Grid (1170, 2 heads), 256 thr = 4 waves.
// Block tile: 32 vox x 64 cout ; wave: 32 vox x 16 cout.
// Per tap: 3 x 32B loads (reg double-buffered) -> 4 MFMAs.
// Non-final: raw bf16 -> raw[head][vox][64slot] + IN stats atomics.
// Final: fp32 channel-last -> d_out.
// ---------------------------------------------------------------------------
template<bool FINAL>
__global__ __launch_bounds__(256) void conv_mfma_kernel(
    const unsigned short* __restrict__ A, const size_t a_head_stride_e,
    const unsigned short* __restrict__ W,
    const float* __restrict__ b_cls, const float* __restrict__ b_reg,
    float* __restrict__ stats, unsigned short* __restrict__ raw,
    float* __restrict__ dout)
{
    const int tid  = threadIdx.x;
    const int head = blockIdx.y;
    const int b    = xcdswz(blockIdx.x);

    int lvl, ls, S, P, loff, cvol, base;
    blkdec(b, lvl, ls, S, P, loff, cvol, base);

    const int lane = tid & 63, wv = tid >> 6;
    const int row = lane & 15, kg = lane >> 4;
    const int cout = wv * 16 + row;

    const unsigned short* Ab = A + (size_t)head * a_head_stride_e + (size_t)cvol * 64;
    const unsigned short* Wh = W + (size_t)head * (27 * 4096);

    int aoff0, aoff1;
    {
        const int v0 = (base - loff) + row;
        const int x = v0 & (S - 1), y = (v0 >> ls) & (S - 1), z = v0 >> (2 * ls);
        aoff0 = (((z + 1) * P + (y + 1)) * P + (x + 1)) * 64 + kg * 16;
        const int v1 = (base - loff) + 16 + row;
        const int x1 = v1 & (S - 1), y1 = (v1 >> ls) & (S - 1), z1 = v1 >> (2 * ls);
        aoff1 = (((z1 + 1) * P + (y1 + 1)) * P + (x1 + 1)) * 64 + kg * 16;
    }
    const int boff = cout * 64 + kg * 16;

    f32x4 acc0 = {0.f,0.f,0.f,0.f}, acc1 = acc0;
    short16 a0A, a1A, bwA, a0B, a1B, bwB;

    auto LD = [&](int t, short16& a0, short16& a1, short16& bw) {
        const int dz = t / 9 - 1, dy = (t / 3) % 3 - 1, dx = t % 3 - 1;
        const int tb = ((dz * P + dy) * P + dx) * 64;
        a0 = *reinterpret_cast<const short16*>(Ab + aoff0 + tb);
        a1 = *reinterpret_cast<const short16*>(Ab + aoff1 + tb);
        bw = *reinterpret_cast<const short16*>(Wh + t * 4096 + boff);
    };
    auto MM = [&](const short16& a0, const short16& a1, const short16& bw) {
        const short8 al0 = __builtin_shufflevector(a0, a0, 0,1,2,3,4,5,6,7);
        const short8 ah0 = __builtin_shufflevector(a0, a0, 8,9,10,11,12,13,14,15);
        const short8 al1 = __builtin_shufflevector(a1, a1, 0,1,2,3,4,5,6,7);
        const short8 ah1 = __builtin_shufflevector(a1, a1, 8,9,10,11,12,13,14,15);
        const short8 bl  = __builtin_shufflevector(bw, bw, 0,1,2,3,4,5,6,7);
        const short8 bh  = __builtin_shufflevector(bw, bw, 8,9,10,11,12,13,14,15);
        acc0 = __builtin_amdgcn_mfma_f32_16x16x32_bf16(al0, bl, acc0, 0, 0, 0);
        acc1 = __builtin_amdgcn_mfma_f32_16x16x32_bf16(al1, bl, acc1, 0, 0, 0);
        acc0 = __builtin_amdgcn_mfma_f32_16x16x32_bf16(ah0, bh, acc0, 0, 0, 0);
        acc1 = __builtin_amdgcn_mfma_f32_16x16x32_bf16(ah1, bh, acc1, 0, 0, 0);
    };

    LD(0, a0A, a1A, bwA);
    for (int t = 0; t < 26; t += 2) {
        LD(t + 1, a0B, a1B, bwB);
        MM(a0A, a1A, bwA);
        LD(t + 2, a0A, a1A, bwA);
        MM(a0B, a1B, bwB);
    }
    MM(a0A, a1A, bwA);

    if constexpr (!FINAL) {
        const float bias = (head ? b_reg : b_cls)[cout];
        const int sp = c2s(cout);
        unsigned short* rp = raw + (size_t)head * RAW_HSTRIDE_E;
        float s1 = 0.f, s2 = 0.f;
        #pragma unroll
        for (int i = 0; i < 2; ++i) {
            const f32x4 a = i ? acc1 : acc0;
            #pragma unroll
            for (int r = 0; r < 4; ++r) {
                const float val = a[r] + bias;
                const int vg = base + i * 16 + kg * 4 + r;   // global voxel id
                rp[(size_t)vg * 64 + sp] = f2b(val);
                s1 += val; s2 += val * val;
            }
        }
        s1 += __shfl_xor(s1, 16, 64); s1 += __shfl_xor(s1, 32, 64);
        s2 += __shfl_xor(s2, 16, 64); s2 += __shfl_xor(s2, 32, 64);
        if (lane < 16) {
            const int spl = c2s(wv * 16 + lane);
            float* st = stats + ((head * 4 + lvl) * 64 + spl) * 2;
            atomicAdd(st + 0, s1);
            atomicAdd(st + 1, s2);
        }
    } else {
        const int OUT = head ? 54 : 18;
        if (cout < OUT) {
            const float bias = (head ? b_reg : b_cls)[cout];
            float* ob = dout + (head ? CLS_TOTAL : 0);
            #pragma unroll
            for (int i = 0; i < 2; ++i) {
                const f32x4 a = i ? acc1 : acc0;
                #pragma unroll
                for (int r = 0; r < 4; ++r) {
                    const int vg = base + i * 16 + kg * 4 + r;
                    ob[(size_t)vg * OUT + cout] = a[r] + bias;
                }
            }
        }
    }
}

// ---------------------------------------------------------------------------
// InstanceNorm + PReLU: raw bf16 [head][vox][64slot] -> padded bf16 dst.
// Grid (1170, 2), same block mapping + swizzle as conv (L2 locality).
// Per thread: one voxel x 8 storage-slots (ushort8). Strict src->dst.
// ---------------------------------------------------------------------------
__global__ __launch_bounds__(256) void norm_kernel(
    const unsigned short* __restrict__ raw, const float* __restrict__ stats,
    const float* __restrict__ a_cls, const float* __restrict__ a_reg,
    const int layer, unsigned short* __restrict__ pad)
{
    const int tid  = threadIdx.x;
    const int head = blockIdx.y;
    const int b    = xcdswz(blockIdx.x);

    int lvl, ls, S, P, loff, cvol, base;
    blkdec(b, lvl, ls, S, P, loff, cvol, base);

    const int vg = base + (tid >> 3);            // global voxel
    const int v  = vg - loff;
    const int s0 = (tid & 7) * 8;
    const int x = v & (S - 1), y = (v >> ls) & (S - 1), z = v >> (2 * ls);
    const int pb = ((z + 1) * P + (y + 1)) * P + (x + 1);

    const float inv_n = 1.0f / (float)(1 << (3 * ls));
    const float alpha = (head ? a_reg : a_cls)[layer];
    const float* st = stats + (size_t)((head * 4 + lvl) * 64) * 2;

    const ushort8 u = *reinterpret_cast<const ushort8*>(
        raw + (size_t)head * RAW_HSTRIDE_E + (size_t)vg * 64 + s0);
    ushort8 o;
    #pragma unroll
    for (int j = 0; j < 8; ++j) {
        const float m = st[(s0 + j) * 2] * inv_n;
        float var = st[(s0 + j) * 2 + 1] * inv_n - m * m;
        const float rs = rsqrtf(fmaxf(var, 0.0f) + 1e-5f);
        float val = (b2f(u[j]) - m) * rs;
        val = (val >= 0.0f) ? val : alpha * val;
        o[j] = f2b(val);
    }
    *reinterpret_cast<ushort8*>(pad + (size_t)head * PAD_HSTRIDE_E
                                    + ((size_t)(cvol + pb) * 64 + s0)) = o;
}

// ---------------------------------------------------------------------------
extern "C" void kernel_launch(void* const* d_in, const int* in_sizes, int n_in,
                              void* d_out, int out_size, void* d_ws, size_t ws_size,
                              hipStream_t stream)
{
    const float* p0      = (const float*)d_in[0];
    const float* p1      = (const float*)d_in[1];
    const float* p2      = (const float*)d_in[2];
    const float* p3      = (const float*)d_in[3];
    const float* cls_w1  = (const float*)d_in[4];
    const float* cls_b1  = (const float*)d_in[5];
    const float* cls_w234= (const float*)d_in[6];
    const float* cls_b234= (const float*)d_in[7];
    const float* cls_a   = (const float*)d_in[8];
    const float* cls_wf  = (const float*)d_in[9];
    const float* cls_bf  = (const float*)d_in[10];
    const float* reg_w1  = (const float*)d_in[11];
    const float* reg_b1  = (const float*)d_in[12];
    const float* reg_w234= (const float*)d_in[13];
    const float* reg_b234= (const float*)d_in[14];
    const float* reg_a   = (const float*)d_in[15];
    const float* reg_wf  = (const float*)d_in[16];
    const float* reg_bf  = (const float*)d_in[17];

    char* ws = (char*)d_ws;
    float*          stats  = (float*)ws;                         // 16,384 B
    unsigned short* padIn0 = (unsigned short*)(ws + 16384);      // 5,933,056 B
    unsigned short* padA   = (unsigned short*)(ws + 5949440);    // 11,866,112 B
    unsigned short* padB   = (unsigned short*)(ws + 17815552);   // 11,866,112 B
    unsigned short* raw    = (unsigned short*)(ws + 29681664);   // 9,584,640 B
    unsigned short* wcvt   = (unsigned short*)(ws + 39266304);   // 2,211,840 B

    // zero stats + all padded activation buffers (pads must be 0 every call);
    // raw and wcvt are fully written before any read each call.
    hipMemsetAsync(ws, 0, 29681664, stream);

    wconv_kernel<<<4320, 256, 0, stream>>>(
        cls_w1, reg_w1, cls_w234, reg_w234, cls_wf, reg_wf, wcvt);
    inconv_kernel<<<1170, 256, 0, stream>>>(p0, p1, p2, p3, padIn0);

    const dim3 cgrid(1170, 2);

    // layer 0: padIn0 (shared heads: stride 0) -> raw -> padA
    conv_mfma_kernel<false><<<cgrid, 256, 0, stream>>>(
        padIn0, 0, wcvt, cls_b1, reg_b1, stats, raw, nullptr);
    norm_kernel<<<cgrid, 256, 0, stream>>>(raw, stats, cls_a, reg_a, 0, padA);

    // layers 1..3: padA -> raw -> padB -> raw -> padA -> raw -> padB
    unsigned short* srcs[3] = { padA, padB, padA };
    unsigned short* dsts[3] = { padB, padA, padB };
    for (int l = 0; l < 3; ++l) {
        conv_mfma_kernel<false><<<cgrid, 256, 0, stream>>>(
            srcs[l], PAD_HSTRIDE_E, wcvt + (size_t)(l + 1) * WLAYER_E,
            cls_b234 + l * 64, reg_b234 + l * 64,
            stats + (l + 1) * 1024, raw, nullptr);
        norm_kernel<<<cgrid, 256, 0, stream>>>(
            raw, stats + (l + 1) * 1024, cls_a, reg_a, l + 1, dsts[l]);
    }

    // final conv: padB -> d_out (channel-last fp32, cls then reg)
    conv_mfma_kernel<true><<<cgrid, 256, 0, stream>>>(
        padB, PAD_HSTRIDE_E, wcvt + 4 * WLAYER_E,
        cls_bf, reg_bf, nullptr, nullptr, (float*)d_out);
}

// Round 8
// 1073.589 us; speedup vs baseline: 1.0304x; 1.0304x over previous
//
#include <hip/hip_runtime.h>

// RetinaNet 3D head via bf16 MFMA implicit GEMM, latency-optimized.
// 2 heads x 4 levels (S=32,16,8,4; vox 32768,4096,512,64; total 37440).
// Activations: zero-padded channel-last bf16 [pvox][64], cin stored in a
// PERMUTED order c2s(c) so one 32B per-lane load covers both K=32 MFMA
// blocks. Weights bf16 [tap][cout][perm cin]. Conv: 27 taps x 2 K-blocks of
// mfma_f32_16x16x32_bf16. THREE-DEEP register prefetch ring (A/B/C) +
// __launch_bounds__(256,4) so the compiler keeps the staging buffers in
// VGPRs (round-7 regression: VGPR=32 -> loads sunk to uses -> serialized
// L2 round-trips). Strict producer->consumer dataflow (no in-place RMW).

typedef __attribute__((ext_vector_type(8)))  short short8;
typedef __attribute__((ext_vector_type(16))) short short16;
typedef __attribute__((ext_vector_type(8)))  unsigned short ushort8;
typedef __attribute__((ext_vector_type(4)))  float f32x4;

static constexpr int TOTVOX    = 37440;
static constexpr int CLS_TOTAL = 673920;                  // 18 * 37440
static constexpr int TOTPADV   = 46352;                   // 39304+5832+1000+216
static constexpr size_t PAD_HSTRIDE_E = (size_t)TOTPADV * 64;  // elems per head
static constexpr size_t RAW_HSTRIDE_E = (size_t)TOTVOX * 64;
static constexpr size_t WLAYER_E = 2u * 27 * 4096;        // elems per layer (2 heads)

__device__ __forceinline__ unsigned short f2b(float x) {
    unsigned int u = __float_as_uint(x);
    u += 0x7FFFu + ((u >> 16) & 1u);
    return (unsigned short)(u >> 16);
}
__device__ __forceinline__ float b2f(unsigned short h) {
    return __uint_as_float(((unsigned)h) << 16);
}
// storage slot -> original channel ; original channel -> storage slot
__device__ __forceinline__ int s2c(int s) { return ((s >> 3) & 1) * 32 + (s >> 4) * 8 + (s & 7); }
__device__ __forceinline__ int c2s(int c) { return ((c >> 3) & 3) * 16 + (c >> 5) * 8 + (c & 7); }

// bijective XCD swizzle for nwg=1170 (q=146, r=2), m204 form
__device__ __forceinline__ int xcdswz(int orig) {
    const int xcd = orig & 7;
    return (xcd < 2 ? xcd * 147 : 294 + (xcd - 2) * 146) + (orig >> 3);
}

// 32-voxel block decomposition: b in [0,1170): l0:1024, l1:128, l2:16, l3:2
__device__ __forceinline__ void blkdec(int b, int& lvl, int& ls, int& S, int& P,
                                       int& loff, int& cvol, int& base)
{
    if (b < 1024)      { lvl = 0; base = b * 32; }
    else if (b < 1152) { lvl = 1; base = 32768 + (b - 1024) * 32; }
    else if (b < 1168) { lvl = 2; base = 36864 + (b - 1152) * 32; }
    else               { lvl = 3; base = 37376 + (b - 1168) * 32; }
    ls = 5 - lvl; S = 1 << ls; P = S + 2;
    loff = (lvl == 0) ? 0 : (lvl == 1) ? 32768 : (lvl == 2) ? 36864 : 37376;
    cvol = (lvl == 0) ? 0 : (lvl == 1) ? 39304 : (lvl == 2) ? 45136 : 46136;
}

__device__ __forceinline__ void voxdec(int vox, int& lvl, int& ls, int& loff,
                                       int& cvol, int& pbase)
{
    if (vox < 32768)      lvl = 0;
    else if (vox < 36864) lvl = 1;
    else if (vox < 37376) lvl = 2;
    else                  lvl = 3;
    ls = 5 - lvl;
    const int S = 1 << ls, P = S + 2;
    loff = (lvl == 0) ? 0 : (lvl == 1) ? 32768 : (lvl == 2) ? 36864 : 37376;
    cvol = (lvl == 0) ? 0 : (lvl == 1) ? 39304 : (lvl == 2) ? 45136 : 46136;
    const int v = vox - loff;
    const int x = v & (S - 1), y = (v >> ls) & (S - 1), z = v >> (2 * ls);
    pbase = ((z + 1) * P + (y + 1)) * P + (x + 1);
}

// ---------------------------------------------------------------------------
// Weight conversion -> bf16 [layer][head][tap][cout(64)][perm cin(64)].
// ---------------------------------------------------------------------------
__global__ __launch_bounds__(256) void wconv_kernel(
    const float* __restrict__ cls_w1, const float* __restrict__ reg_w1,
    const float* __restrict__ cls_w234, const float* __restrict__ reg_w234,
    const float* __restrict__ cls_wf, const float* __restrict__ reg_wf,
    unsigned short* __restrict__ dst)
{
    const int id = blockIdx.x * 256 + (int)threadIdx.x;   // < 1,105,920
    const int s  = id / 221184;
    const int r  = id - s * 221184;
    const int head = r / 110592;
    const int r2 = r - head * 110592;
    const int t  = r2 >> 12;
    const int co = (r2 >> 6) & 63;
    const int cio = s2c(r2 & 63);

    float val = 0.0f;
    if (s == 0) {
        if (cio < 36) {
            const float* w = head ? reg_w1 : cls_w1;      // [64][36][27]
            val = w[(co * 36 + cio) * 27 + t];
        }
    } else if (s <= 3) {
        const float* w = (head ? reg_w234 : cls_w234) + (size_t)(s - 1) * 110592;
        val = w[(co * 64 + cio) * 27 + t];                // [64][64][27]
    } else {
        const int OUT = head ? 54 : 18;
        if (co < OUT) {
            const float* w = head ? reg_wf : cls_wf;      // [OUT][64][27]
            val = w[(co * 64 + cio) * 27 + t];
        }
    }
    dst[id] = f2b(val);
}

// ---------------------------------------------------------------------------
// Input conversion: p0..p3 fp32 [36][nvox] -> padded bf16 [pvox][64] permuted.
// ---------------------------------------------------------------------------
__global__ __launch_bounds__(256) void inconv_kernel(
    const float* __restrict__ p0, const float* __restrict__ p1,
    const float* __restrict__ p2, const float* __restrict__ p3,
    unsigned short* __restrict__ padin)
{
    const int id = blockIdx.x * 256 + (int)threadIdx.x;   // < 299,520
    const int cbi = id / 37440;
    const int vox = id - cbi * 37440;
    const int s0 = cbi * 8;

    int lvl, ls, loff, cvol, pbase;
    voxdec(vox, lvl, ls, loff, cvol, pbase);
    const int nvox = 1 << (3 * ls);
    const int lvox = vox - loff;
    const float* src = (lvl == 0) ? p0 : (lvl == 1) ? p1 : (lvl == 2) ? p2 : p3;

    ushort8 o;
    #pragma unroll
    for (int j = 0; j < 8; ++j) {
        const int c = s2c(s0 + j);
        o[j] = (c < 36) ? f2b(src[c * nvox + lvox]) : (unsigned short)0;
    }
    *reinterpret_cast<ushort8*>(padin + ((size_t)(cvol + pbase) * 64 + s0)) = o;
}

// ---------------------------------------------------------------------------
// Conv layer: implicit GEMM. Grid (1170, 2 heads), 256 thr = 4 waves.
// Block tile: 32 vox x 64 cout ; wave: 32 vox x 16 cout.
// Per tap: 3 x 32B loads; 3-deep prefetch ring; 4 MFMAs per tap.
// ---------------------------------------------------------------------------
template<bool FINAL>
__global__ __launch_bounds__(256, 4) void conv_mfma_kernel(
    const unsigned short* __restrict__ A, const size_t a_head_stride_e,
    const unsigned short* __restrict__ W,
    const float* __restrict__ b_cls, const float* __restrict__ b_reg,
    float* __restrict__ stats, unsigned short* __restrict__ raw,
    float* __restrict__ dout)
{
    const int tid  = threadIdx.x;
    const int head = blockIdx.y;
    const int b    = xcdswz(blockIdx.x);

    int lvl, ls, S, P, loff, cvol, base;
    blkdec(b, lvl, ls, S, P, loff, cvol, base);

    const int lane = tid & 63, wv = tid >> 6;
    const int row = lane & 15, kg = lane >> 4;
    const int cout = wv * 16 + row;

    const unsigned short* Ab = A + (size_t)head * a_head_stride_e + (size_t)cvol * 64;
    const unsigned short* Wh = W + (size_t)head * (27 * 4096);

    int aoff0, aoff1;
    {
        const int v0 = (base - loff) + row;
        const int x = v0 & (S - 1), y = (v0 >> ls) & (S - 1), z = v0 >> (2 * ls);
        aoff0 = (((z + 1) * P + (y + 1)) * P + (x + 1)) * 64 + kg * 16;
        const int v1 = (base - loff) + 16 + row;
        const int x1 = v1 & (S - 1), y1 = (v1 >> ls) & (S - 1), z1 = v1 >> (2 * ls);
        aoff1 = (((z1 + 1) * P + (y1 + 1)) * P + (x1 + 1)) * 64 + kg * 16;
    }
    const int boff = cout * 64 + kg * 16;

    f32x4 acc0 = {0.f,0.f,0.f,0.f}, acc1 = acc0;

    // 3-deep prefetch ring
    short16 a0A, a1A, bwA, a0B, a1B, bwB, a0C, a1C, bwC;

    auto LD = [&](int t, short16& a0, short16& a1, short16& bw) {
        const int dz = t / 9 - 1, dy = (t / 3) % 3 - 1, dx = t % 3 - 1;
        const int tb = ((dz * P + dy) * P + dx) * 64;
        a0 = *reinterpret_cast<const short16*>(Ab + aoff0 + tb);
        a1 = *reinterpret_cast<const short16*>(Ab + aoff1 + tb);
        bw = *reinterpret_cast<const short16*>(Wh + t * 4096 + boff);
    };
    auto MM = [&](const short16& a0, const short16& a1, const short16& bw) {
        const short8 al0 = __builtin_shufflevector(a0, a0, 0,1,2,3,4,5,6,7);
        const short8 ah0 = __builtin_shufflevector(a0, a0, 8,9,10,11,12,13,14,15);
        const short8 al1 = __builtin_shufflevector(a1, a1, 0,1,2,3,4,5,6,7);
        const short8 ah1 = __builtin_shufflevector(a1, a1, 8,9,10,11,12,13,14,15);
        const short8 bl  = __builtin_shufflevector(bw, bw, 0,1,2,3,4,5,6,7);
        const short8 bh  = __builtin_shufflevector(bw, bw, 8,9,10,11,12,13,14,15);
        acc0 = __builtin_amdgcn_mfma_f32_16x16x32_bf16(al0, bl, acc0, 0, 0, 0);
        acc1 = __builtin_amdgcn_mfma_f32_16x16x32_bf16(al1, bl, acc1, 0, 0, 0);
        acc0 = __builtin_amdgcn_mfma_f32_16x16x32_bf16(ah0, bh, acc0, 0, 0, 0);
        acc1 = __builtin_amdgcn_mfma_f32_16x16x32_bf16(ah1, bh, acc1, 0, 0, 0);
    };

    LD(0, a0A, a1A, bwA);
    LD(1, a0B, a1B, bwB);
    LD(2, a0C, a1C, bwC);
    #pragma unroll
    for (int t = 0; t < 27; t += 3) {
        MM(a0A, a1A, bwA);
        if (t + 3 < 27) LD(t + 3, a0A, a1A, bwA);
        MM(a0B, a1B, bwB);
        if (t + 4 < 27) LD(t + 4, a0B, a1B, bwB);
        MM(a0C, a1C, bwC);
        if (t + 5 < 27) LD(t + 5, a0C, a1C, bwC);
    }

    if constexpr (!FINAL) {
        const float bias = (head ? b_reg : b_cls)[cout];
        const int sp = c2s(cout);
        unsigned short* rp = raw + (size_t)head * RAW_HSTRIDE_E;
        float s1 = 0.f, s2 = 0.f;
        #pragma unroll
        for (int i = 0; i < 2; ++i) {
            const f32x4 a = i ? acc1 : acc0;
            #pragma unroll
            for (int r = 0; r < 4; ++r) {
                const float val = a[r] + bias;
                const int vg = base + i * 16 + kg * 4 + r;   // global voxel id
                rp[(size_t)vg * 64 + sp] = f2b(val);
                s1 += val; s2 += val * val;
            }
        }
        s1 += __shfl_xor(s1, 16, 64); s1 += __shfl_xor(s1, 32, 64);
        s2 += __shfl_xor(s2, 16, 64); s2 += __shfl_xor(s2, 32, 64);
        if (lane < 16) {
            const int spl = c2s(wv * 16 + lane);
            float* st = stats + ((head * 4 + lvl) * 64 + spl) * 2;
            atomicAdd(st + 0, s1);
            atomicAdd(st + 1, s2);
        }
    } else {
        const int OUT = head ? 54 : 18;
        if (cout < OUT) {
            const float bias = (head ? b_reg : b_cls)[cout];
            float* ob = dout + (head ? CLS_TOTAL : 0);
            #pragma unroll
            for (int i = 0; i < 2; ++i) {
                const f32x4 a = i ? acc1 : acc0;
                #pragma unroll
                for (int r = 0; r < 4; ++r) {
                    const int vg = base + i * 16 + kg * 4 + r;
                    ob[(size_t)vg * OUT + cout] = a[r] + bias;
                }
            }
        }
    }
}

// ---------------------------------------------------------------------------
// InstanceNorm + PReLU: raw bf16 [head][vox][64slot] -> padded bf16 dst.
// Grid (1170, 2), same block mapping + swizzle as conv (L2 locality).
// Per thread: one voxel x 8 storage-slots (ushort8). Strict src->dst.
// ---------------------------------------------------------------------------
__global__ __launch_bounds__(256) void norm_kernel(
    const unsigned short* __restrict__ raw, const float* __restrict__ stats,
    const float* __restrict__ a_cls, const float* __restrict__ a_reg,
    const int layer, unsigned short* __restrict__ pad)
{
    const int tid  = threadIdx.x;
    const int head = blockIdx.y;
    const int b    = xcdswz(blockIdx.x);

    int lvl, ls, S, P, loff, cvol, base;
    blkdec(b, lvl, ls, S, P, loff, cvol, base);

    const int vg = base + (tid >> 3);            // global voxel
    const int v  = vg - loff;
    const int s0 = (tid & 7) * 8;
    const int x = v & (S - 1), y = (v >> ls) & (S - 1), z = v >> (2 * ls);
    const int pb = ((z + 1) * P + (y + 1)) * P + (x + 1);

    const float inv_n = 1.0f / (float)(1 << (3 * ls));
    const float alpha = (head ? a_reg : a_cls)[layer];
    const float* st = stats + (size_t)((head * 4 + lvl) * 64) * 2;

    const ushort8 u = *reinterpret_cast<const ushort8*>(
        raw + (size_t)head * RAW_HSTRIDE_E + (size_t)vg * 64 + s0);
    ushort8 o;
    #pragma unroll
    for (int j = 0; j < 8; ++j) {
        const float m = st[(s0 + j) * 2] * inv_n;
        float var = st[(s0 + j) * 2 + 1] * inv_n - m * m;
        const float rs = rsqrtf(fmaxf(var, 0.0f) + 1e-5f);
        float val = (b2f(u[j]) - m) * rs;
        val = (val >= 0.0f) ? val : alpha * val;
        o[j] = f2b(val);
    }
    *reinterpret_cast<ushort8*>(pad + (size_t)head * PAD_HSTRIDE_E
                                    + ((size_t)(cvol + pb) * 64 + s0)) = o;
}

// ---------------------------------------------------------------------------
extern "C" void kernel_launch(void* const* d_in, const int* in_sizes, int n_in,
                              void* d_out, int out_size, void* d_ws, size_t ws_size,
                              hipStream_t stream)
{
    const float* p0      = (const float*)d_in[0];
    const float* p1      = (const float*)d_in[1];
    const float* p2      = (const float*)d_in[2];
    const float* p3      = (const float*)d_in[3];
    const float* cls_w1  = (const float*)d_in[4];
    const float* cls_b1  = (const float*)d_in[5];
    const float* cls_w234= (const float*)d_in[6];
    const float* cls_b234= (const float*)d_in[7];
    const float* cls_a   = (const float*)d_in[8];
    const float* cls_wf  = (const float*)d_in[9];
    const float* cls_bf  = (const float*)d_in[10];
    const float* reg_w1  = (const float*)d_in[11];
    const float* reg_b1  = (const float*)d_in[12];
    const float* reg_w234= (const float*)d_in[13];
    const float* reg_b234= (const float*)d_in[14];
    const float* reg_a   = (const float*)d_in[15];
    const float* reg_wf  = (const float*)d_in[16];
    const float* reg_bf  = (const float*)d_in[17];

    char* ws = (char*)d_ws;
    float*          stats  = (float*)ws;                         // 16,384 B
    unsigned short* padIn0 = (unsigned short*)(ws + 16384);      // 5,933,056 B
    unsigned short* padA   = (unsigned short*)(ws + 5949440);    // 11,866,112 B
    unsigned short* padB   = (unsigned short*)(ws + 17815552);   // 11,866,112 B
    unsigned short* raw    = (unsigned short*)(ws + 29681664);   // 9,584,640 B
    unsigned short* wcvt   = (unsigned short*)(ws + 39266304);   // 2,211,840 B

    // zero stats + all padded activation buffers (pads must be 0 every call);
    // raw and wcvt are fully written before any read each call.
    hipMemsetAsync(ws, 0, 29681664, stream);

    wconv_kernel<<<4320, 256, 0, stream>>>(
        cls_w1, reg_w1, cls_w234, reg_w234, cls_wf, reg_wf, wcvt);
    inconv_kernel<<<1170, 256, 0, stream>>>(p0, p1, p2, p3, padIn0);

    const dim3 cgrid(1170, 2);

    // layer 0: padIn0 (shared heads: stride 0) -> raw -> padA
    conv_mfma_kernel<false><<<cgrid, 256, 0, stream>>>(
        padIn0, 0, wcvt, cls_b1, reg_b1, stats, raw, nullptr);
    norm_kernel<<<cgrid, 256, 0, stream>>>(raw, stats, cls_a, reg_a, 0, padA);

    // layers 1..3: padA -> raw -> padB -> raw -> padA -> raw -> padB
    unsigned short* srcs[3] = { padA, padB, padA };
    unsigned short* dsts[3] = { padB, padA, padB };
    for (int l = 0; l < 3; ++l) {
        conv_mfma_kernel<false><<<cgrid, 256, 0, stream>>>(
            srcs[l], PAD_HSTRIDE_E, wcvt + (size_t)(l + 1) * WLAYER_E,
            cls_b234 + l * 64, reg_b234 + l * 64,
            stats + (l + 1) * 1024, raw, nullptr);
        norm_kernel<<<cgrid, 256, 0, stream>>>(
            raw, stats + (l + 1) * 1024, cls_a, reg_a, l + 1, dsts[l]);
    }

    // final conv: padB -> d_out (channel-last fp32, cls then reg)
    conv_mfma_kernel<true><<<cgrid, 256, 0, stream>>>(
        padB, PAD_HSTRIDE_E, wcvt + 4 * WLAYER_E,
        cls_bf, reg_bf, nullptr, nullptr, (float*)d_out);
}

// Round 9
// 1071.257 us; speedup vs baseline: 1.0327x; 1.0022x over previous
//
#include <hip/hip_runtime.h>

// RetinaNet 3D head via bf16 MFMA implicit GEMM.
// 2 heads x 4 levels (S=32,16,8,4; vox 32768,4096,512,64; total 37440).
// Activations: zero-padded channel-last bf16 [pvox][64], cin stored PERMUTED
// (c2s) so one 32B per-lane region covers both K=32 MFMA blocks (lo/hi 16B).
// Weights bf16 [tap][cout][perm cin]. Conv: 27 taps x 2 K-blocks of
// mfma_f32_16x16x32_bf16.
// Round-9 core: INLINE-ASM global_load_dwordx4 (SGPR base + VGPR voffset)
// with a 3-tap register ring and counted s_waitcnt vmcnt(12/6/0) +
// sched_barrier(0) — hipcc provably sinks C-level loads (r7: VGPR=32,
// r8: VGPR=36), serializing ~81 L2-latency round trips per wave. Volatile
// asm pins issue order; 18 loads stay in flight.
// Strict producer->consumer dataflow (no in-place RMW — replay-safe).

typedef __attribute__((ext_vector_type(8)))  short short8;
typedef __attribute__((ext_vector_type(8)))  unsigned short ushort8;
typedef __attribute__((ext_vector_type(4)))  float f32x4;

static constexpr int TOTVOX    = 37440;
static constexpr int CLS_TOTAL = 673920;                  // 18 * 37440
static constexpr int TOTPADV   = 46352;                   // 39304+5832+1000+216
static constexpr size_t PAD_HSTRIDE_E = (size_t)TOTPADV * 64;  // elems per head
static constexpr size_t RAW_HSTRIDE_E = (size_t)TOTVOX * 64;
static constexpr size_t WLAYER_E = 2u * 27 * 4096;        // elems per layer (2 heads)

__device__ __forceinline__ unsigned short f2b(float x) {
    unsigned int u = __float_as_uint(x);
    u += 0x7FFFu + ((u >> 16) & 1u);
    return (unsigned short)(u >> 16);
}
__device__ __forceinline__ float b2f(unsigned short h) {
    return __uint_as_float(((unsigned)h) << 16);
}
// storage slot -> original channel ; original channel -> storage slot
__device__ __forceinline__ int s2c(int s) { return ((s >> 3) & 1) * 32 + (s >> 4) * 8 + (s & 7); }
__device__ __forceinline__ int c2s(int c) { return ((c >> 3) & 3) * 16 + (c >> 5) * 8 + (c & 7); }

// bijective XCD swizzle for nwg=1170 (q=146, r=2), m204 form
__device__ __forceinline__ int xcdswz(int orig) {
    const int xcd = orig & 7;
    return (xcd < 2 ? xcd * 147 : 294 + (xcd - 2) * 146) + (orig >> 3);
}

// 32-voxel block decomposition: b in [0,1170): l0:1024, l1:128, l2:16, l3:2
__device__ __forceinline__ void blkdec(int b, int& lvl, int& ls, int& S, int& P,
                                       int& loff, int& cvol, int& base)
{
    if (b < 1024)      { lvl = 0; base = b * 32; }
    else if (b < 1152) { lvl = 1; base = 32768 + (b - 1024) * 32; }
    else if (b < 1168) { lvl = 2; base = 36864 + (b - 1152) * 32; }
    else               { lvl = 3; base = 37376 + (b - 1168) * 32; }
    ls = 5 - lvl; S = 1 << ls; P = S + 2;
    loff = (lvl == 0) ? 0 : (lvl == 1) ? 32768 : (lvl == 2) ? 36864 : 37376;
    cvol = (lvl == 0) ? 0 : (lvl == 1) ? 39304 : (lvl == 2) ? 45136 : 46136;
}

__device__ __forceinline__ void voxdec(int vox, int& lvl, int& ls, int& loff,
                                       int& cvol, int& pbase)
{
    if (vox < 32768)      lvl = 0;
    else if (vox < 36864) lvl = 1;
    else if (vox < 37376) lvl = 2;
    else                  lvl = 3;
    ls = 5 - lvl;
    const int S = 1 << ls, P = S + 2;
    loff = (lvl == 0) ? 0 : (lvl == 1) ? 32768 : (lvl == 2) ? 36864 : 37376;
    cvol = (lvl == 0) ? 0 : (lvl == 1) ? 39304 : (lvl == 2) ? 45136 : 46136;
    const int v = vox - loff;
    const int x = v & (S - 1), y = (v >> ls) & (S - 1), z = v >> (2 * ls);
    pbase = ((z + 1) * P + (y + 1)) * P + (x + 1);
}

// ---------------------------------------------------------------------------
// Weight conversion -> bf16 [layer][head][tap][cout(64)][perm cin(64)].
// ---------------------------------------------------------------------------
__global__ __launch_bounds__(256) void wconv_kernel(
    const float* __restrict__ cls_w1, const float* __restrict__ reg_w1,
    const float* __restrict__ cls_w234, const float* __restrict__ reg_w234,
    const float* __restrict__ cls_wf, const float* __restrict__ reg_wf,
    unsigned short* __restrict__ dst)
{
    const int id = blockIdx.x * 256 + (int)threadIdx.x;   // < 1,105,920
    const int s  = id / 221184;
    const int r  = id - s * 221184;
    const int head = r / 110592;
    const int r2 = r - head * 110592;
    const int t  = r2 >> 12;
    const int co = (r2 >> 6) & 63;
    const int cio = s2c(r2 & 63);

    float val = 0.0f;
    if (s == 0) {
        if (cio < 36) {
            const float* w = head ? reg_w1 : cls_w1;      // [64][36][27]
            val = w[(co * 36 + cio) * 27 + t];
        }
    } else if (s <= 3) {
        const float* w = (head ? reg_w234 : cls_w234) + (size_t)(s - 1) * 110592;
        val = w[(co * 64 + cio) * 27 + t];                // [64][64][27]
    } else {
        const int OUT = head ? 54 : 18;
        if (co < OUT) {
            const float* w = head ? reg_wf : cls_wf;      // [OUT][64][27]
            val = w[(co * 64 + cio) * 27 + t];
        }
    }
    dst[id] = f2b(val);
}

// ---------------------------------------------------------------------------
// Input conversion: p0..p3 fp32 [36][nvox] -> padded bf16 [pvox][64] permuted.
// ---------------------------------------------------------------------------
__global__ __launch_bounds__(256) void inconv_kernel(
    const float* __restrict__ p0, const float* __restrict__ p1,
    const float* __restrict__ p2, const float* __restrict__ p3,
    unsigned short* __restrict__ padin)
{
    const int id = blockIdx.x * 256 + (int)threadIdx.x;   // < 299,520
    const int cbi = id / 37440;
    const int vox = id - cbi * 37440;
    const int s0 = cbi * 8;

    int lvl, ls, loff, cvol, pbase;
    voxdec(vox, lvl, ls, loff, cvol, pbase);
    const int nvox = 1 << (3 * ls);
    const int lvox = vox - loff;
    const float* src = (lvl == 0) ? p0 : (lvl == 1) ? p1 : (lvl == 2) ? p2 : p3;

    ushort8 o;
    #pragma unroll
    for (int j = 0; j < 8; ++j) {
        const int c = s2c(s0 + j);
        o[j] = (c < 36) ? f2b(src[c * nvox + lvox]) : (unsigned short)0;
    }
    *reinterpret_cast<ushort8*>(padin + ((size_t)(cvol + pbase) * 64 + s0)) = o;
}

// ---------------------------------------------------------------------------
// Conv layer: implicit GEMM. Grid (1170, 2 heads), 256 thr = 4 waves.
// Block tile: 32 vox x 64 cout ; wave: 32 vox x 16 cout.
// Inline-asm loads, 3-tap ring, counted vmcnt. 4 MFMAs per tap.
// ---------------------------------------------------------------------------
template<bool FINAL>
__global__ __launch_bounds__(256, 4) void conv_mfma_kernel(
    const unsigned short* __restrict__ A, const size_t a_head_stride_e,
    const unsigned short* __restrict__ W,
    const float* __restrict__ b_cls, const float* __restrict__ b_reg,
    float* __restrict__ stats, unsigned short* __restrict__ raw,
    float* __restrict__ dout)
{
    const int tid  = threadIdx.x;
    const int head = blockIdx.y;
    const int b    = xcdswz(blockIdx.x);

    int lvl, ls, S, P, loff, cvol, base;
    blkdec(b, lvl, ls, S, P, loff, cvol, base);

    const int lane = tid & 63, wv = tid >> 6;
    const int row = lane & 15, kg = lane >> 4;
    const int cout = wv * 16 + row;

    const unsigned short* Ab = A + (size_t)head * a_head_stride_e + (size_t)cvol * 64;
    const unsigned short* Wh = W + (size_t)head * (27 * 4096);

    unsigned avB0, avB1;
    {
        const int v0 = (base - loff) + row;
        const int x = v0 & (S - 1), y = (v0 >> ls) & (S - 1), z = v0 >> (2 * ls);
        avB0 = (unsigned)((((z + 1) * P + (y + 1)) * P + (x + 1)) * 128 + kg * 32);
        const int v1 = (base - loff) + 16 + row;
        const int x1 = v1 & (S - 1), y1 = (v1 >> ls) & (S - 1), z1 = v1 >> (2 * ls);
        avB1 = (unsigned)((((z1 + 1) * P + (y1 + 1)) * P + (x1 + 1)) * 128 + kg * 32);
    }
    const unsigned bvB = (unsigned)(cout * 128 + kg * 32);

    f32x4 acc0 = {0.f,0.f,0.f,0.f}, acc1 = acc0;

    // 3-slot register ring, 6 short8 per slot (A0 lo/hi, A1 lo/hi, W lo/hi)
    short8 A0l0,A0h0,A1l0,A1h0,Bl0,Bh0;
    short8 A0l1,A0h1,A1l1,A1h1,Bl1,Bh1;
    short8 A0l2,A0h2,A1l2,A1h2,Bl2,Bh2;

    auto ISSUE = [&](int t, short8& a0l, short8& a0h, short8& a1l, short8& a1h,
                     short8& bl, short8& bh) {
        const int dz = t / 9 - 1, dy = (t / 3) % 3 - 1, dx = t % 3 - 1;
        const int tb = ((dz * P + dy) * P + dx) * 64;
        const unsigned short* At = Ab + tb;
        const unsigned short* Wt = Wh + t * 4096;
        asm volatile("global_load_dwordx4 %0, %2, %3 offset:0\n\t"
                     "global_load_dwordx4 %1, %2, %3 offset:16"
                     : "=&v"(a0l), "=&v"(a0h) : "v"(avB0), "s"(At));
        asm volatile("global_load_dwordx4 %0, %2, %3 offset:0\n\t"
                     "global_load_dwordx4 %1, %2, %3 offset:16"
                     : "=&v"(a1l), "=&v"(a1h) : "v"(avB1), "s"(At));
        asm volatile("global_load_dwordx4 %0, %2, %3 offset:0\n\t"
                     "global_load_dwordx4 %1, %2, %3 offset:16"
                     : "=&v"(bl), "=&v"(bh) : "v"(bvB), "s"(Wt));
    };
    auto CONS = [&](const short8& a0l, const short8& a0h, const short8& a1l,
                    const short8& a1h, const short8& bl, const short8& bh) {
        acc0 = __builtin_amdgcn_mfma_f32_16x16x32_bf16(a0l, bl, acc0, 0, 0, 0);
        acc1 = __builtin_amdgcn_mfma_f32_16x16x32_bf16(a1l, bl, acc1, 0, 0, 0);
        acc0 = __builtin_amdgcn_mfma_f32_16x16x32_bf16(a0h, bh, acc0, 0, 0, 0);
        acc1 = __builtin_amdgcn_mfma_f32_16x16x32_bf16(a1h, bh, acc1, 0, 0, 0);
    };

    #define SLOT0 A0l0,A0h0,A1l0,A1h0,Bl0,Bh0
    #define SLOT1 A0l1,A0h1,A1l1,A1h1,Bl1,Bh1
    #define SLOT2 A0l2,A0h2,A1l2,A1h2,Bl2,Bh2
    #define WAITV(N) do { asm volatile("s_waitcnt vmcnt(" #N ")" ::: "memory"); \
                          __builtin_amdgcn_sched_barrier(0); } while (0)

    ISSUE(0, SLOT0); ISSUE(1, SLOT1); ISSUE(2, SLOT2);
    WAITV(12); CONS(SLOT0); ISSUE(3,  SLOT0);
    WAITV(12); CONS(SLOT1); ISSUE(4,  SLOT1);
    WAITV(12); CONS(SLOT2); ISSUE(5,  SLOT2);
    WAITV(12); CONS(SLOT0); ISSUE(6,  SLOT0);
    WAITV(12); CONS(SLOT1); ISSUE(7,  SLOT1);
    WAITV(12); CONS(SLOT2); ISSUE(8,  SLOT2);
    WAITV(12); CONS(SLOT0); ISSUE(9,  SLOT0);
    WAITV(12); CONS(SLOT1); ISSUE(10, SLOT1);
    WAITV(12); CONS(SLOT2); ISSUE(11, SLOT2);
    WAITV(12); CONS(SLOT0); ISSUE(12, SLOT0);
    WAITV(12); CONS(SLOT1); ISSUE(13, SLOT1);
    WAITV(12); CONS(SLOT2); ISSUE(14, SLOT2);
    WAITV(12); CONS(SLOT0); ISSUE(15, SLOT0);
    WAITV(12); CONS(SLOT1); ISSUE(16, SLOT1);
    WAITV(12); CONS(SLOT2); ISSUE(17, SLOT2);
    WAITV(12); CONS(SLOT0); ISSUE(18, SLOT0);
    WAITV(12); CONS(SLOT1); ISSUE(19, SLOT1);
    WAITV(12); CONS(SLOT2); ISSUE(20, SLOT2);
    WAITV(12); CONS(SLOT0); ISSUE(21, SLOT0);
    WAITV(12); CONS(SLOT1); ISSUE(22, SLOT1);
    WAITV(12); CONS(SLOT2); ISSUE(23, SLOT2);
    WAITV(12); CONS(SLOT0); ISSUE(24, SLOT0);
    WAITV(12); CONS(SLOT1); ISSUE(25, SLOT1);
    WAITV(12); CONS(SLOT2); ISSUE(26, SLOT2);
    WAITV(12); CONS(SLOT0);
    WAITV(6);  CONS(SLOT1);
    WAITV(0);  CONS(SLOT2);

    #undef SLOT0
    #undef SLOT1
    #undef SLOT2
    #undef WAITV

    if constexpr (!FINAL) {
        const float bias = (head ? b_reg : b_cls)[cout];
        const int sp = c2s(cout);
        unsigned short* rp = raw + (size_t)head * RAW_HSTRIDE_E;
        float s1 = 0.f, s2 = 0.f;
        #pragma unroll
        for (int i = 0; i < 2; ++i) {
            const f32x4 a = i ? acc1 : acc0;
            #pragma unroll
            for (int r = 0; r < 4; ++r) {
                const float val = a[r] + bias;
                const int vg = base + i * 16 + kg * 4 + r;   // global voxel id
                rp[(size_t)vg * 64 + sp] = f2b(val);
                s1 += val; s2 += val * val;
            }
        }
        s1 += __shfl_xor(s1, 16, 64); s1 += __shfl_xor(s1, 32, 64);
        s2 += __shfl_xor(s2, 16, 64); s2 += __shfl_xor(s2, 32, 64);
        if (lane < 16) {
            const int spl = c2s(wv * 16 + lane);
            float* st = stats + ((head * 4 + lvl) * 64 + spl) * 2;
            atomicAdd(st + 0, s1);
            atomicAdd(st + 1, s2);
        }
    } else {
        const int OUT = head ? 54 : 18;
        if (cout < OUT) {
            const float bias = (head ? b_reg : b_cls)[cout];
            float* ob = dout + (head ? CLS_TOTAL : 0);
            #pragma unroll
            for (int i = 0; i < 2; ++i) {
                const f32x4 a = i ? acc1 : acc0;
                #pragma unroll
                for (int r = 0; r < 4; ++r) {
                    const int vg = base + i * 16 + kg * 4 + r;
                    ob[(size_t)vg * OUT + cout] = a[r] + bias;
                }
            }
        }
    }
}

// ---------------------------------------------------------------------------
// InstanceNorm + PReLU: raw bf16 [head][vox][64slot] -> padded bf16 dst.
// Grid (1170, 2), same block mapping + swizzle as conv (L2 locality).
// Per thread: one voxel x 8 storage-slots (ushort8). Strict src->dst.
// ---------------------------------------------------------------------------
__global__ __launch_bounds__(256) void norm_kernel(
    const unsigned short* __restrict__ raw, const float* __restrict__ stats,
    const float* __restrict__ a_cls, const float* __restrict__ a_reg,
    const int layer, unsigned short* __restrict__ pad)
{
    const int tid  = threadIdx.x;
    const int head = blockIdx.y;
    const int b    = xcdswz(blockIdx.x);

    int lvl, ls, S, P, loff, cvol, base;
    blkdec(b, lvl, ls, S, P, loff, cvol, base);

    const int vg = base + (tid >> 3);            // global voxel
    const int v  = vg - loff;
    const int s0 = (tid & 7) * 8;
    const int x = v & (S - 1), y = (v >> ls) & (S - 1), z = v >> (2 * ls);
    const int pb = ((z + 1) * P + (y + 1)) * P + (x + 1);

    const float inv_n = 1.0f / (float)(1 << (3 * ls));
    const float alpha = (head ? a_reg : a_cls)[layer];
    const float* st = stats + (size_t)((head * 4 + lvl) * 64) * 2;

    const ushort8 u = *reinterpret_cast<const ushort8*>(
        raw + (size_t)head * RAW_HSTRIDE_E + (size_t)vg * 64 + s0);
    ushort8 o;
    #pragma unroll
    for (int j = 0; j < 8; ++j) {
        const float m = st[(s0 + j) * 2] * inv_n;
        float var = st[(s0 + j) * 2 + 1] * inv_n - m * m;
        const float rs = rsqrtf(fmaxf(var, 0.0f) + 1e-5f);
        float val = (b2f(u[j]) - m) * rs;
        val = (val >= 0.0f) ? val : alpha * val;
        o[j] = f2b(val);
    }
    *reinterpret_cast<ushort8*>(pad + (size_t)head * PAD_HSTRIDE_E
                                    + ((size_t)(cvol + pb) * 64 + s0)) = o;
}

// ---------------------------------------------------------------------------
extern "C" void kernel_launch(void* const* d_in, const int* in_sizes, int n_in,
                              void* d_out, int out_size, void* d_ws, size_t ws_size,
                              hipStream_t stream)
{
    const float* p0      = (const float*)d_in[0];
    const float* p1      = (const float*)d_in[1];
    const float* p2      = (const float*)d_in[2];
    const float* p3      = (const float*)d_in[3];
    const float* cls_w1  = (const float*)d_in[4];
    const float* cls_b1  = (const float*)d_in[5];
    const float* cls_w234= (const float*)d_in[6];
    const float* cls_b234= (const float*)d_in[7];
    const float* cls_a   = (const float*)d_in[8];
    const float* cls_wf  = (const float*)d_in[9];
    const float* cls_bf  = (const float*)d_in[10];
    const float* reg_w1  = (const float*)d_in[11];
    const float* reg_b1  = (const float*)d_in[12];
    const float* reg_w234= (const float*)d_in[13];
    const float* reg_b234= (const float*)d_in[14];
    const float* reg_a   = (const float*)d_in[15];
    const float* reg_wf  = (const float*)d_in[16];
    const float* reg_bf  = (const float*)d_in[17];

    char* ws = (char*)d_ws;
    float*          stats  = (float*)ws;                         // 16,384 B
    unsigned short* padIn0 = (unsigned short*)(ws + 16384);      // 5,933,056 B
    unsigned short* padA   = (unsigned short*)(ws + 5949440);    // 11,866,112 B
    unsigned short* padB   = (unsigned short*)(ws + 17815552);   // 11,866,112 B
    unsigned short* raw    = (unsigned short*)(ws + 29681664);   // 9,584,640 B
    unsigned short* wcvt   = (unsigned short*)(ws + 39266304);   // 2,211,840 B

    // zero stats + all padded activation buffers (pads must be 0 every call);
    // raw and wcvt are fully written before any read each call.
    hipMemsetAsync(ws, 0, 29681664, stream);

    wconv_kernel<<<4320, 256, 0, stream>>>(
        cls_w1, reg_w1, cls_w234, reg_w234, cls_wf, reg_wf, wcvt);
    inconv_kernel<<<1170, 256, 0, stream>>>(p0, p1, p2, p3, padIn0);

    const dim3 cgrid(1170, 2);

    // layer 0: padIn0 (shared heads: stride 0) -> raw -> padA
    conv_mfma_kernel<false><<<cgrid, 256, 0, stream>>>(
        padIn0, 0, wcvt, cls_b1, reg_b1, stats, raw, nullptr);
    norm_kernel<<<cgrid, 256, 0, stream>>>(raw, stats, cls_a, reg_a, 0, padA);

    // layers 1..3: padA -> raw -> padB -> raw -> padA -> raw -> padB
    unsigned short* srcs[3] = { padA, padB, padA };
    unsigned short* dsts[3] = { padB, padA, padB };
    for (int l = 0; l < 3; ++l) {
        conv_mfma_kernel<false><<<cgrid, 256, 0, stream>>>(
            srcs[l], PAD_HSTRIDE_E, wcvt + (size_t)(l + 1) * WLAYER_E,
            cls_b234 + l * 64, reg_b234 + l * 64,
            stats + (l + 1) * 1024, raw, nullptr);
        norm_kernel<<<cgrid, 256, 0, stream>>>(
            raw, stats + (l + 1) * 1024, cls_a, reg_a, l + 1, dsts[l]);
    }

    // final conv: padB -> d_out (channel-last fp32, cls then reg)
    conv_mfma_kernel<true><<<cgrid, 256, 0, stream>>>(
        padB, PAD_HSTRIDE_E, wcvt + 4 * WLAYER_E,
        cls_bf, reg_bf, nullptr, nullptr, (float*)d_out);
}

// Round 10
// 557.198 us; speedup vs baseline: 1.9854x; 1.9226x over previous
//
#include <hip/hip_runtime.h>

// RetinaNet 3D head via bf16 MFMA implicit GEMM.
// 2 heads x 4 levels (S=32,16,8,4; vox 32768,4096,512,64; total 37440).
//
// Round-10 core: SLICE-MAJOR layouts so every global load is full-cache-line:
//   activations: [head][slice(8)][pvox][8ch] (16B per (slice,vox))
//   weights:     [layer][head][tap][kb(2)][kg(4)][cout(64)][8ch]
// A-fragment load: lane(kg*16+row) reads 16B at slice(kb*4+kg) + vox(row)*16
//   -> lanes 0..15 contiguous 256B (fully-consumed lines). Same for W.
// (r9 layout read 16B per lane at stride 128B: 32 half-consumed lines per
//  load instruction -> L1 line-throughput bound at ~195us/dispatch.)
// Inline-asm loads, 3-tap register ring, counted s_waitcnt vmcnt(12/6/0)
// + sched_barrier(0). Strict producer->consumer dataflow (replay-safe).

typedef __attribute__((ext_vector_type(8)))  short short8;
typedef __attribute__((ext_vector_type(8)))  unsigned short ushort8;
typedef __attribute__((ext_vector_type(4)))  float f32x4;

static constexpr int TOTVOX    = 37440;
static constexpr int CLS_TOTAL = 673920;                  // 18 * 37440
static constexpr int TOTPADV   = 46352;                   // 39304+5832+1000+216
static constexpr size_t PAD_HSTRIDE_E = (size_t)TOTPADV * 64;  // elems per head
static constexpr size_t WLAYER_E = 2u * 27 * 4096;        // elems per layer (2 heads)

__device__ __forceinline__ unsigned short f2b(float x) {
    unsigned int u = __float_as_uint(x);
    u += 0x7FFFu + ((u >> 16) & 1u);
    return (unsigned short)(u >> 16);
}
__device__ __forceinline__ float b2f(unsigned short h) {
    return __uint_as_float(((unsigned)h) << 16);
}

// bijective XCD swizzle for nwg=1170 (q=146, r=2), m204 form
__device__ __forceinline__ int xcdswz(int orig) {
    const int xcd = orig & 7;
    return (xcd < 2 ? xcd * 147 : 294 + (xcd - 2) * 146) + (orig >> 3);
}

// 32-voxel block decomposition: b in [0,1170): l0:1024, l1:128, l2:16, l3:2
__device__ __forceinline__ void blkdec(int b, int& lvl, int& ls, int& S, int& P,
                                       int& loff, int& cvol, int& base)
{
    if (b < 1024)      { lvl = 0; base = b * 32; }
    else if (b < 1152) { lvl = 1; base = 32768 + (b - 1024) * 32; }
    else if (b < 1168) { lvl = 2; base = 36864 + (b - 1152) * 32; }
    else               { lvl = 3; base = 37376 + (b - 1168) * 32; }
    ls = 5 - lvl; S = 1 << ls; P = S + 2;
    loff = (lvl == 0) ? 0 : (lvl == 1) ? 32768 : (lvl == 2) ? 36864 : 37376;
    cvol = (lvl == 0) ? 0 : (lvl == 1) ? 39304 : (lvl == 2) ? 45136 : 46136;
}

__device__ __forceinline__ void voxdec(int vox, int& lvl, int& ls, int& loff,
                                       int& cvol, int& pbase)
{
    if (vox < 32768)      lvl = 0;
    else if (vox < 36864) lvl = 1;
    else if (vox < 37376) lvl = 2;
    else                  lvl = 3;
    ls = 5 - lvl;
    const int S = 1 << ls, P = S + 2;
    loff = (lvl == 0) ? 0 : (lvl == 1) ? 32768 : (lvl == 2) ? 36864 : 37376;
    cvol = (lvl == 0) ? 0 : (lvl == 1) ? 39304 : (lvl == 2) ? 45136 : 46136;
    const int v = vox - loff;
    const int x = v & (S - 1), y = (v >> ls) & (S - 1), z = v >> (2 * ls);
    pbase = ((z + 1) * P + (y + 1)) * P + (x + 1);
}

// ---------------------------------------------------------------------------
// Weight conversion -> bf16 [layer][head][tap][kb][kg][cout(64)][8ch].
// ---------------------------------------------------------------------------
__global__ __launch_bounds__(256) void wconv_kernel(
    const float* __restrict__ cls_w1, const float* __restrict__ reg_w1,
    const float* __restrict__ cls_w234, const float* __restrict__ reg_w234,
    const float* __restrict__ cls_wf, const float* __restrict__ reg_wf,
    unsigned short* __restrict__ dst)
{
    const int id = blockIdx.x * 256 + (int)threadIdx.x;   // < 1,105,920
    const int s  = id / 221184;
    const int r  = id - s * 221184;
    const int head = r / 110592;
    const int r2 = r - head * 110592;
    const int t  = r2 >> 12;
    const int q  = r2 & 4095;
    const int slice = q >> 9;          // kb*4+kg
    const int co = (q >> 3) & 63;
    const int ci = slice * 8 + (q & 7);

    float val = 0.0f;
    if (s == 0) {
        if (ci < 36) {
            const float* w = head ? reg_w1 : cls_w1;      // [64][36][27]
            val = w[(co * 36 + ci) * 27 + t];
        }
    } else if (s <= 3) {
        const float* w = (head ? reg_w234 : cls_w234) + (size_t)(s - 1) * 110592;
        val = w[(co * 64 + ci) * 27 + t];                 // [64][64][27]
    } else {
        const int OUT = head ? 54 : 18;
        if (co < OUT) {
            const float* w = head ? reg_wf : cls_wf;      // [OUT][64][27]
            val = w[(co * 64 + ci) * 27 + t];
        }
    }
    dst[id] = f2b(val);
}

// ---------------------------------------------------------------------------
// Input conversion: p0..p3 fp32 [36][nvox] -> padded slice-major bf16.
// Thread: one (slice, vox) pair -> one 16B store.
// ---------------------------------------------------------------------------
__global__ __launch_bounds__(256) void inconv_kernel(
    const float* __restrict__ p0, const float* __restrict__ p1,
    const float* __restrict__ p2, const float* __restrict__ p3,
    unsigned short* __restrict__ padin)
{
    const int id = blockIdx.x * 256 + (int)threadIdx.x;   // < 299,520
    const int s   = id / 37440;
    const int vox = id - s * 37440;

    int lvl, ls, loff, cvol, pbase;
    voxdec(vox, lvl, ls, loff, cvol, pbase);
    const int nvox = 1 << (3 * ls);
    const int lvox = vox - loff;
    const float* src = (lvl == 0) ? p0 : (lvl == 1) ? p1 : (lvl == 2) ? p2 : p3;

    ushort8 o;
    #pragma unroll
    for (int j = 0; j < 8; ++j) {
        const int c = s * 8 + j;
        o[j] = (c < 36) ? f2b(src[c * nvox + lvox]) : (unsigned short)0;
    }
    *reinterpret_cast<ushort8*>(padin + ((size_t)s * TOTPADV + cvol + pbase) * 8) = o;
}

// ---------------------------------------------------------------------------
// Conv layer: implicit GEMM. Grid (1170, 2 heads), 256 thr = 4 waves.
// Block tile: 32 vox x 64 cout ; wave: 32 vox x 16 cout.
// Per tap: 6 x 16B full-line loads (asm, 3-tap ring, counted vmcnt);
// 4 MFMAs per tap.
// ---------------------------------------------------------------------------
template<bool FINAL>
__global__ __launch_bounds__(256, 4) void conv_mfma_kernel(
    const unsigned short* __restrict__ A, const size_t a_head_stride_e,
    const unsigned short* __restrict__ W,
    const float* __restrict__ b_cls, const float* __restrict__ b_reg,
    float* __restrict__ stats, unsigned short* __restrict__ raw,
    float* __restrict__ dout)
{
    const int tid  = threadIdx.x;
    const int head = blockIdx.y;
    const int b    = xcdswz(blockIdx.x);

    int lvl, ls, S, P, loff, cvol, base;
    blkdec(b, lvl, ls, S, P, loff, cvol, base);

    const int lane = tid & 63, wv = tid >> 6;
    const int row = lane & 15, kg = lane >> 4;
    const int cout = wv * 16 + row;

    const unsigned short* Abase = A + (size_t)head * a_head_stride_e;
    const unsigned short* Wh = W + (size_t)head * (27 * 4096);

    // per-lane byte voffsets (constant across taps; tap folded into SGPR base)
    unsigned av00, av01, av10, av11, wv0, wv1;
    {
        const int v0 = (base - loff) + row;
        const int x0 = v0 & (S - 1), y0 = (v0 >> ls) & (S - 1), z0 = v0 >> (2 * ls);
        const int pb0 = ((z0 + 1) * P + (y0 + 1)) * P + (x0 + 1);
        const int v1 = (base - loff) + 16 + row;
        const int x1 = v1 & (S - 1), y1 = (v1 >> ls) & (S - 1), z1 = v1 >> (2 * ls);
        const int pb1 = ((z1 + 1) * P + (y1 + 1)) * P + (x1 + 1);
        av00 = (unsigned)(((kg)     * TOTPADV + cvol + pb0) * 16);
        av01 = (unsigned)(((kg + 4) * TOTPADV + cvol + pb0) * 16);
        av10 = (unsigned)(((kg)     * TOTPADV + cvol + pb1) * 16);
        av11 = (unsigned)(((kg + 4) * TOTPADV + cvol + pb1) * 16);
    }
    wv0 = (unsigned)(((kg)     * 64 + cout) * 16);
    wv1 = (unsigned)(((kg + 4) * 64 + cout) * 16);

    f32x4 acc0 = {0.f,0.f,0.f,0.f}, acc1 = acc0;

    // 3-slot register ring, 6 short8 per slot
    short8 a00_0,a01_0,a10_0,a11_0,w0_0,w1_0;
    short8 a00_1,a01_1,a10_1,a11_1,w0_1,w1_1;
    short8 a00_2,a01_2,a10_2,a11_2,w0_2,w1_2;

    auto ISSUE = [&](int t, short8& a00, short8& a01, short8& a10, short8& a11,
                     short8& w0, short8& w1) {
        const int dz = t / 9 - 1, dy = (t / 3) % 3 - 1, dx = t % 3 - 1;
        const unsigned short* At = Abase + (size_t)((dz * P + dy) * P + dx) * 8;
        const unsigned short* Wt = Wh + t * 4096;
        asm volatile("global_load_dwordx4 %0, %1, %2" : "=v"(a00) : "v"(av00), "s"(At));
        asm volatile("global_load_dwordx4 %0, %1, %2" : "=v"(a01) : "v"(av01), "s"(At));
        asm volatile("global_load_dwordx4 %0, %1, %2" : "=v"(a10) : "v"(av10), "s"(At));
        asm volatile("global_load_dwordx4 %0, %1, %2" : "=v"(a11) : "v"(av11), "s"(At));
        asm volatile("global_load_dwordx4 %0, %1, %2" : "=v"(w0)  : "v"(wv0),  "s"(Wt));
        asm volatile("global_load_dwordx4 %0, %1, %2" : "=v"(w1)  : "v"(wv1),  "s"(Wt));
    };
    auto CONS = [&](const short8& a00, const short8& a01, const short8& a10,
                    const short8& a11, const short8& w0, const short8& w1) {
        acc0 = __builtin_amdgcn_mfma_f32_16x16x32_bf16(a00, w0, acc0, 0, 0, 0);
        acc1 = __builtin_amdgcn_mfma_f32_16x16x32_bf16(a10, w0, acc1, 0, 0, 0);
        acc0 = __builtin_amdgcn_mfma_f32_16x16x32_bf16(a01, w1, acc0, 0, 0, 0);
        acc1 = __builtin_amdgcn_mfma_f32_16x16x32_bf16(a11, w1, acc1, 0, 0, 0);
    };

    #define SLOT0 a00_0,a01_0,a10_0,a11_0,w0_0,w1_0
    #define SLOT1 a00_1,a01_1,a10_1,a11_1,w0_1,w1_1
    #define SLOT2 a00_2,a01_2,a10_2,a11_2,w0_2,w1_2
    #define WAITV(N) do { asm volatile("s_waitcnt vmcnt(" #N ")" ::: "memory"); \
                          __builtin_amdgcn_sched_barrier(0); } while (0)

    ISSUE(0, SLOT0); ISSUE(1, SLOT1); ISSUE(2, SLOT2);
    WAITV(12); CONS(SLOT0); ISSUE(3,  SLOT0);
    WAITV(12); CONS(SLOT1); ISSUE(4,  SLOT1);
    WAITV(12); CONS(SLOT2); ISSUE(5,  SLOT2);
    WAITV(12); CONS(SLOT0); ISSUE(6,  SLOT0);
    WAITV(12); CONS(SLOT1); ISSUE(7,  SLOT1);
    WAITV(12); CONS(SLOT2); ISSUE(8,  SLOT2);
    WAITV(12); CONS(SLOT0); ISSUE(9,  SLOT0);
    WAITV(12); CONS(SLOT1); ISSUE(10, SLOT1);
    WAITV(12); CONS(SLOT2); ISSUE(11, SLOT2);
    WAITV(12); CONS(SLOT0); ISSUE(12, SLOT0);
    WAITV(12); CONS(SLOT1); ISSUE(13, SLOT1);
    WAITV(12); CONS(SLOT2); ISSUE(14, SLOT2);
    WAITV(12); CONS(SLOT0); ISSUE(15, SLOT0);
    WAITV(12); CONS(SLOT1); ISSUE(16, SLOT1);
    WAITV(12); CONS(SLOT2); ISSUE(17, SLOT2);
    WAITV(12); CONS(SLOT0); ISSUE(18, SLOT0);
    WAITV(12); CONS(SLOT1); ISSUE(19, SLOT1);
    WAITV(12); CONS(SLOT2); ISSUE(20, SLOT2);
    WAITV(12); CONS(SLOT0); ISSUE(21, SLOT0);
    WAITV(12); CONS(SLOT1); ISSUE(22, SLOT1);
    WAITV(12); CONS(SLOT2); ISSUE(23, SLOT2);
    WAITV(12); CONS(SLOT0); ISSUE(24, SLOT0);
    WAITV(12); CONS(SLOT1); ISSUE(25, SLOT1);
    WAITV(12); CONS(SLOT2); ISSUE(26, SLOT2);
    WAITV(12); CONS(SLOT0);
    WAITV(6);  CONS(SLOT1);
    WAITV(0);  CONS(SLOT2);

    #undef SLOT0
    #undef SLOT1
    #undef SLOT2
    #undef WAITV

    if constexpr (!FINAL) {
        const float bias = (head ? b_reg : b_cls)[cout];
        // raw layout: [head][slice=cout>>3][vox][8ch]
        unsigned short* rp = raw + ((size_t)(head * 8 + (cout >> 3)) * TOTVOX) * 8
                                 + (cout & 7);
        float s1 = 0.f, s2 = 0.f;
        #pragma unroll
        for (int i = 0; i < 2; ++i) {
            const f32x4 a = i ? acc1 : acc0;
            #pragma unroll
            for (int r = 0; r < 4; ++r) {
                const float val = a[r] + bias;
                const int vg = base + i * 16 + kg * 4 + r;   // global voxel id
                rp[(size_t)vg * 8] = f2b(val);
                s1 += val; s2 += val * val;
            }
        }
        s1 += __shfl_xor(s1, 16, 64); s1 += __shfl_xor(s1, 32, 64);
        s2 += __shfl_xor(s2, 16, 64); s2 += __shfl_xor(s2, 32, 64);
        if (lane < 16) {
            float* st = stats + ((head * 4 + lvl) * 64 + wv * 16 + lane) * 2;
            atomicAdd(st + 0, s1);
            atomicAdd(st + 1, s2);
        }
    } else {
        const int OUT = head ? 54 : 18;
        if (cout < OUT) {
            const float bias = (head ? b_reg : b_cls)[cout];
            float* ob = dout + (head ? CLS_TOTAL : 0);
            #pragma unroll
            for (int i = 0; i < 2; ++i) {
                const f32x4 a = i ? acc1 : acc0;
                #pragma unroll
                for (int r = 0; r < 4; ++r) {
                    const int vg = base + i * 16 + kg * 4 + r;
                    ob[(size_t)vg * OUT + cout] = a[r] + bias;
                }
            }
        }
    }
}

// ---------------------------------------------------------------------------
// InstanceNorm + PReLU: raw [head][slice][vox][8] -> padded slice-major dst.
// Grid (1170, 2), same block mapping + swizzle as conv (L2 locality).
// Per thread: one (slice, vox) pair (16B in, 16B out). Strict src->dst.
// ---------------------------------------------------------------------------
__global__ __launch_bounds__(256) void norm_kernel(
    const unsigned short* __restrict__ raw, const float* __restrict__ stats,
    const float* __restrict__ a_cls, const float* __restrict__ a_reg,
    const int layer, unsigned short* __restrict__ pad)
{
    const int tid  = threadIdx.x;
    const int head = blockIdx.y;
    const int b    = xcdswz(blockIdx.x);

    int lvl, ls, S, P, loff, cvol, base;
    blkdec(b, lvl, ls, S, P, loff, cvol, base);

    const int vg = base + (tid >> 3);            // global voxel
    const int v  = vg - loff;
    const int s  = tid & 7;                      // slice
    const int x = v & (S - 1), y = (v >> ls) & (S - 1), z = v >> (2 * ls);
    const int pb = ((z + 1) * P + (y + 1)) * P + (x + 1);

    const float inv_n = 1.0f / (float)(1 << (3 * ls));
    const float alpha = (head ? a_reg : a_cls)[layer];
    const float* st = stats + (size_t)((head * 4 + lvl) * 64) * 2;

    const ushort8 u = *reinterpret_cast<const ushort8*>(
        raw + ((size_t)(head * 8 + s) * TOTVOX + vg) * 8);
    ushort8 o;
    #pragma unroll
    for (int j = 0; j < 8; ++j) {
        const int c = s * 8 + j;
        const float m = st[c * 2] * inv_n;
        float var = st[c * 2 + 1] * inv_n - m * m;
        const float rs = rsqrtf(fmaxf(var, 0.0f) + 1e-5f);
        float val = (b2f(u[j]) - m) * rs;
        val = (val >= 0.0f) ? val : alpha * val;
        o[j] = f2b(val);
    }
    *reinterpret_cast<ushort8*>(pad + (size_t)head * PAD_HSTRIDE_E
                                    + ((size_t)s * TOTPADV + cvol + pb) * 8) = o;
}

// ---------------------------------------------------------------------------
extern "C" void kernel_launch(void* const* d_in, const int* in_sizes, int n_in,
                              void* d_out, int out_size, void* d_ws, size_t ws_size,
                              hipStream_t stream)
{
    const float* p0      = (const float*)d_in[0];
    const float* p1      = (const float*)d_in[1];
    const float* p2      = (const float*)d_in[2];
    const float* p3      = (const float*)d_in[3];
    const float* cls_w1  = (const float*)d_in[4];
    const float* cls_b1  = (const float*)d_in[5];
    const float* cls_w234= (const float*)d_in[6];
    const float* cls_b234= (const float*)d_in[7];
    const float* cls_a   = (const float*)d_in[8];
    const float* cls_wf  = (const float*)d_in[9];
    const float* cls_bf  = (const float*)d_in[10];
    const float* reg_w1  = (const float*)d_in[11];
    const float* reg_b1  = (const float*)d_in[12];
    const float* reg_w234= (const float*)d_in[13];
    const float* reg_b234= (const float*)d_in[14];
    const float* reg_a   = (const float*)d_in[15];
    const float* reg_wf  = (const float*)d_in[16];
    const float* reg_bf  = (const float*)d_in[17];

    char* ws = (char*)d_ws;
    float*          stats  = (float*)ws;                         // 16,384 B
    unsigned short* padIn0 = (unsigned short*)(ws + 16384);      // 5,933,056 B
    unsigned short* padA   = (unsigned short*)(ws + 5949440);    // 11,866,112 B
    unsigned short* padB   = (unsigned short*)(ws + 17815552);   // 11,866,112 B
    unsigned short* raw    = (unsigned short*)(ws + 29681664);   // 9,584,640 B
    unsigned short* wcvt   = (unsigned short*)(ws + 39266304);   // 2,211,840 B

    // zero stats + all padded activation buffers (pads must be 0 every call);
    // raw and wcvt are fully written before any read each call.
    hipMemsetAsync(ws, 0, 29681664, stream);

    wconv_kernel<<<4320, 256, 0, stream>>>(
        cls_w1, reg_w1, cls_w234, reg_w234, cls_wf, reg_wf, wcvt);
    inconv_kernel<<<1170, 256, 0, stream>>>(p0, p1, p2, p3, padIn0);

    const dim3 cgrid(1170, 2);

    // layer 0: padIn0 (shared heads: stride 0) -> raw -> padA
    conv_mfma_kernel<false><<<cgrid, 256, 0, stream>>>(
        padIn0, 0, wcvt, cls_b1, reg_b1, stats, raw, nullptr);
    norm_kernel<<<cgrid, 256, 0, stream>>>(raw, stats, cls_a, reg_a, 0, padA);

    // layers 1..3: padA -> raw -> padB -> raw -> padA -> raw -> padB
    unsigned short* srcs[3] = { padA, padB, padA };
    unsigned short* dsts[3] = { padB, padA, padB };
    for (int l = 0; l < 3; ++l) {
        conv_mfma_kernel<false><<<cgrid, 256, 0, stream>>>(
            srcs[l], PAD_HSTRIDE_E, wcvt + (size_t)(l + 1) * WLAYER_E,
            cls_b234 + l * 64, reg_b234 + l * 64,
            stats + (l + 1) * 1024, raw, nullptr);
        norm_kernel<<<cgrid, 256, 0, stream>>>(
            raw, stats + (l + 1) * 1024, cls_a, reg_a, l + 1, dsts[l]);
    }

    // final conv: padB -> d_out (channel-last fp32, cls then reg)
    conv_mfma_kernel<true><<<cgrid, 256, 0, stream>>>(
        padB, PAD_HSTRIDE_E, wcvt + 4 * WLAYER_E,
        cls_bf, reg_bf, nullptr, nullptr, (float*)d_out);
}